// Round 17
// baseline (967.309 us; speedup 1.0000x reference)
//
#include <hip/hip_runtime.h>
#include <math.h>

#define N_NODES  50000
#define N_EDGES  800000
#define N_GRAPHS 5000
#define N_PAIRS  4096
#define F_IN     9
#define H        64
#define NCHUNK   49   // ceil(50000/1024)
#define WPAD     68   // transposed-weight row stride: 272B = 16B-aligned

__device__ __forceinline__ float fast_tanh(float x) {
    float e = __expf(-2.0f * fabsf(x));
    float t = __fdividef(1.0f - e, 1.0f + e);
    return copysignf(t, x);
}

__device__ __forceinline__ float bf2f(unsigned short u) {
    union { unsigned int i; float f; } v; v.i = ((unsigned int)u) << 16; return v.f;
}
__device__ __forceinline__ unsigned short f2bf(float f) {
    union { float f; unsigned int i; } v; v.f = f;
    unsigned int u = v.i;
    return (unsigned short)((u + 0x7FFFu + ((u >> 16) & 1u)) >> 16);
}

__device__ __forceinline__ int lbound(const int* __restrict__ a, int n, int v) {
    int lo = 0, hi = n;
    while (lo < hi) { int m = (lo + hi) >> 1; if (a[m] < v) lo = m + 1; else hi = m; }
    return lo;
}

// ---------------- degree + per-edge rank (atomic return value IS the rank) --------

__global__ void k_deg_rank(const int* __restrict__ dst, int* __restrict__ degi,
                           unsigned char* __restrict__ rank) {
    int i = blockIdx.x * blockDim.x + threadIdx.x;
    if (i < N_EDGES) rank[i] = (unsigned char)atomicAdd(&degi[dst[i]], 1);
}

// ---------------- dis + xs = x*dis + chunk sums (merged) ----------------

__global__ void k_dis_chunksum(const int* __restrict__ degi, const float* __restrict__ x,
                               float* __restrict__ dis, float* __restrict__ xs,
                               int* __restrict__ chunksum) {
    __shared__ int wsum[4];
    int t = threadIdx.x, lane = t & 63, wi = t >> 6;
    int base_i = blockIdx.x * 1024 + t * 4;
    int s = 0;
#pragma unroll
    for (int k = 0; k < 4; ++k) {
        int i = base_i + k;
        if (i < N_NODES) {
            int dg = degi[i];
            s += dg;
            float d = rsqrtf((float)dg + 1.0f);
            dis[i] = d;
#pragma unroll
            for (int j = 0; j < F_IN; ++j) xs[i * F_IN + j] = x[i * F_IN + j] * d;
        }
    }
    for (int o = 32; o > 0; o >>= 1) s += __shfl_down(s, o, 64);
    if (lane == 0) wsum[wi] = s;
    __syncthreads();
    if (t == 0) chunksum[blockIdx.x] = wsum[0] + wsum[1] + wsum[2] + wsum[3];
}

__global__ void k_scanchunks(const int* __restrict__ chunksum, int* __restrict__ chunkbase,
                             int* __restrict__ off) {
    int lane = threadIdx.x;
    int v = (lane < NCHUNK) ? chunksum[lane] : 0;
    int inc = v;
    for (int o = 1; o < 64; o <<= 1) {
        int u = __shfl_up(inc, o, 64);
        if (lane >= o) inc += u;
    }
    if (lane < NCHUNK) chunkbase[lane] = inc - v;
    if (lane == 0) off[N_NODES] = N_EDGES;
}

__global__ void k_scan(const int* __restrict__ degi, const int* __restrict__ chunkbase,
                       int* __restrict__ off) {
    __shared__ int wsum[4];
    int t = threadIdx.x, lane = t & 63, wi = t >> 6;
    int base_i = blockIdx.x * 1024 + t * 4;
    int v[4];
    int s = 0;
#pragma unroll
    for (int k = 0; k < 4; ++k) {
        int i = base_i + k;
        v[k] = (i < N_NODES) ? degi[i] : 0;
        s += v[k];
    }
    int inc = s;
    for (int o = 1; o < 64; o <<= 1) {
        int u = __shfl_up(inc, o, 64);
        if (lane >= o) inc += u;
    }
    if (lane == 63) wsum[wi] = inc;
    __syncthreads();
    int wbase = 0;
    for (int w = 0; w < 4; ++w) if (w < wi) wbase += wsum[w];
    int ex = chunkbase[blockIdx.x] + wbase + inc - s;
#pragma unroll
    for (int k = 0; k < 4; ++k) {
        int i = base_i + k;
        if (i < N_NODES) off[i] = ex;
        ex += v[k];
    }
}

// CSR entry = u32 src byte-offset (src<<7). pos = off[dst]+rank, no atomic.
__global__ void k_fill(const int* __restrict__ src, const int* __restrict__ dst,
                       const unsigned char* __restrict__ rank,
                       const int* __restrict__ off, unsigned int* __restrict__ csr32) {
    int e = blockIdx.x * blockDim.x + threadIdx.x;
    if (e < N_EDGES) {
        int d = dst[e];
        int pos = off[d] + (int)rank[e];
        csr32[pos] = (unsigned int)(src[e] << 7);
    }
}

// ---------------- layer 1 fused: agg xs (9-wide) -> *dis -> LDS -> mm+tanh*dis -------

__global__ __launch_bounds__(256) void k_layer1(
        const float* __restrict__ xs, const int* __restrict__ off,
        const unsigned int* __restrict__ csr32,
        const float* __restrict__ dis, const float* __restrict__ W,
        const float* __restrict__ b, unsigned short* __restrict__ h) {
    __shared__ float sW[F_IN * H];
    __shared__ float sb[H];
    __shared__ float sax[16][F_IN + 1];   // +1 pad
    __shared__ float sdis[16];
    for (int t = threadIdx.x; t < F_IN * H; t += 256) sW[t] = W[t];
    if (threadIdx.x < H) sb[threadIdx.x] = b[threadIdx.x];

    // phase 1: 16-lane group per node (lanes 0..8 active)
    int g = threadIdx.x >> 4, l = threadIdx.x & 15;
    int node = blockIdx.x * 16 + g;
    if (node < N_NODES && l < F_IN) {
        int beg = off[node], end = off[node + 1];
        float d = dis[node];
        float acc = xs[node * F_IN + l];
        for (int e = beg; e < end; ++e) {
            int s = (int)(csr32[e] >> 7);
            acc += xs[s * F_IN + l];
        }
        sax[g][l] = acc * d;
        if (l == 0) sdis[g] = d;
    }
    __syncthreads();

    // phase 2: 4 rows per wave; output hs = tanh * dis (folded for next layer)
    int wi = threadIdx.x >> 6, j = threadIdx.x & 63;
    for (int r = 0; r < 4; ++r) {
        int row = blockIdx.x * 16 + wi * 4 + r;
        if (row >= N_NODES) break;
        float acc = sb[j];
#pragma unroll
        for (int k = 0; k < F_IN; ++k) acc += sax[wi * 4 + r][k] * sW[k * H + j];
        h[row * H + j] = f2bf(fast_tanh(acc) * sdis[wi * 4 + r]);
    }
}

// ---------------- fused layer: sum(hs) -> *dis -> @W + b -> tanh [*dis] -> bf16 -------
// R14 depth-2 pipeline on u32 entries; inner loop is pure {load, gather, add}.

__global__ __launch_bounds__(256) void k_gmm(
        const unsigned short* __restrict__ hin, const int* __restrict__ off,
        const unsigned int* __restrict__ csr32,
        const float* __restrict__ dis, const float* __restrict__ W,
        const float* __restrict__ b, unsigned short* __restrict__ hout,
        const int fold) {
    __shared__ float sWt[H][WPAD];   // sWt[j][k] = W[k][j]
    __shared__ float sb[H];
    __shared__ float srow[4][H];
    for (int t = threadIdx.x; t < H * H; t += 256) {
        int k = t >> 6, jx = t & 63;
        sWt[jx][k] = W[t];
    }
    if (threadIdx.x < H) sb[threadIdx.x] = b[threadIdx.x];
    __syncthreads();
    int wi = threadIdx.x >> 6, j = threadIdx.x & 63;
    const char* hbase = (const char*)hin + (j << 1);   // per-lane feature offset
    for (int it = 0; it < 8; ++it) {
        int node = blockIdx.x * 32 + wi * 8 + it;
        if (node >= N_NODES) break;
        int beg = off[node], end = off[node + 1];
        float d = dis[node];
        float acc = bf2f(hin[node * H + j]);   // self term: dis*(hs_i + sum)
        int nfull = (end - beg) >> 2;
        int e = beg + (nfull << 2);
        const unsigned int* cp = csr32 + beg;

        if (nfull >= 2) {
            unsigned int a0 = cp[0], a1 = cp[1], a2 = cp[2], a3 = cp[3];
            unsigned int b0 = cp[4], b1 = cp[5], b2 = cp[6], b3 = cp[7];
            float va0 = bf2f(*(const unsigned short*)(hbase + a0));
            float va1 = bf2f(*(const unsigned short*)(hbase + a1));
            float va2 = bf2f(*(const unsigned short*)(hbase + a2));
            float va3 = bf2f(*(const unsigned short*)(hbase + a3));
            for (int bi = 1; bi < nfull - 1; ++bi) {
                float vb0 = bf2f(*(const unsigned short*)(hbase + b0));
                float vb1 = bf2f(*(const unsigned short*)(hbase + b1));
                float vb2 = bf2f(*(const unsigned short*)(hbase + b2));
                float vb3 = bf2f(*(const unsigned short*)(hbase + b3));
                const unsigned int* np = cp + ((bi + 1) << 2);
                unsigned int c0 = np[0], c1 = np[1], c2 = np[2], c3 = np[3];
                acc += (va0 + va1) + (va2 + va3);
                a0 = b0; a1 = b1; a2 = b2; a3 = b3;
                va0 = vb0; va1 = vb1; va2 = vb2; va3 = vb3;
                b0 = c0; b1 = c1; b2 = c2; b3 = c3;
            }
            float vb0 = bf2f(*(const unsigned short*)(hbase + b0));
            float vb1 = bf2f(*(const unsigned short*)(hbase + b1));
            float vb2 = bf2f(*(const unsigned short*)(hbase + b2));
            float vb3 = bf2f(*(const unsigned short*)(hbase + b3));
            acc += (va0 + va1) + (va2 + va3);
            acc += (vb0 + vb1) + (vb2 + vb3);
        } else if (nfull == 1) {
            float v0 = bf2f(*(const unsigned short*)(hbase + cp[0]));
            float v1 = bf2f(*(const unsigned short*)(hbase + cp[1]));
            float v2 = bf2f(*(const unsigned short*)(hbase + cp[2]));
            float v3 = bf2f(*(const unsigned short*)(hbase + cp[3]));
            acc += (v0 + v1) + (v2 + v3);
        }
        for (; e < end; ++e)
            acc += bf2f(*(const unsigned short*)(hbase + csr32[e]));

        srow[wi][j] = acc * d;      // wave-local write then read: in-order per wave
        float a = sb[j];
#pragma unroll
        for (int kb = 0; kb < H; kb += 4) {
            float4 g4 = *(const float4*)&srow[wi][kb];   // uniform-addr broadcast
            float4 w4 = *(const float4*)&sWt[j][kb];     // per-lane b128
            a += g4.x * w4.x + g4.y * w4.y + g4.z * w4.z + g4.w * w4.w;
        }
        float t = fast_tanh(a);
        hout[node * H + j] = f2bf(fold ? t * d : t);
    }
}

// ---------------- fused MLP + graph pool: ONE LANE PER NODE ----------------
// Zero DS-pipe usage: activations in VGPRs (8x uint4 per lane, 128B-contiguous
// rows), weights read with wave-uniform indices -> scalar-pipe s_load broadcast
// through the constant cache. No LDS reads, no shuffles; one atomic per lane.

__global__ __launch_bounds__(256) void k_mlp(
        const unsigned short* __restrict__ h, const int* __restrict__ batch,
        const float* __restrict__ fc1w, const float* __restrict__ fc1b,
        const float* __restrict__ fc2w, const float* __restrict__ fc2b,
        const float* __restrict__ fc3w, const float* __restrict__ fc3b,
        float* __restrict__ sums) {
    int node = blockIdx.x * blockDim.x + threadIdx.x;
    if (node >= N_NODES) return;

    // unpack this node's 64 bf16 activations into registers
    float hv[H];
    const uint4* hp4 = (const uint4*)(h + (size_t)node * H);
#pragma unroll
    for (int q = 0; q < 8; ++q) {
        uint4 r = hp4[q];
        hv[q * 8 + 0] = bf2f((unsigned short)(r.x & 0xFFFF));
        hv[q * 8 + 1] = bf2f((unsigned short)(r.x >> 16));
        hv[q * 8 + 2] = bf2f((unsigned short)(r.y & 0xFFFF));
        hv[q * 8 + 3] = bf2f((unsigned short)(r.y >> 16));
        hv[q * 8 + 4] = bf2f((unsigned short)(r.z & 0xFFFF));
        hv[q * 8 + 5] = bf2f((unsigned short)(r.z >> 16));
        hv[q * 8 + 6] = bf2f((unsigned short)(r.w & 0xFFFF));
        hv[q * 8 + 7] = bf2f((unsigned short)(r.w >> 16));
    }

    // fc2 accumulators (static indices via full unroll)
    float a2[32];
#pragma unroll
    for (int c = 0; c < 32; ++c) a2[c] = 0.f;

    // fc1 output o -> tanh -> fold into fc2 accumulators immediately
#pragma unroll
    for (int o = 0; o < H; ++o) {
        float acc = fc1b[o];
#pragma unroll
        for (int k = 0; k < H; ++k) acc += hv[k] * fc1w[k * H + o];
        float s1 = fast_tanh(acc);
#pragma unroll
        for (int c = 0; c < 32; ++c) a2[c] += s1 * fc2w[o * 32 + c];
    }

    float val = fc3b[0];
#pragma unroll
    for (int c = 0; c < 32; ++c) val += fast_tanh(a2[c] + fc2b[c]) * fc3w[c];

    atomicAdd(&sums[batch[node]], val);
}

// ---------------- readout: util + pairs (cnt via binary search, merged) ----------------

__global__ void k_finish(const float* __restrict__ sums, const int* __restrict__ batch,
                         const int* __restrict__ ia, const int* __restrict__ ib,
                         float* __restrict__ out_pairs, float* __restrict__ out_util) {
    int i = blockIdx.x * blockDim.x + threadIdx.x;
    if (i < N_GRAPHS) {
        int c = lbound(batch, N_NODES, i + 1) - lbound(batch, N_NODES, i);
        out_util[i] = sums[i] / fmaxf((float)c, 1.0f);
    }
    if (i < N_PAIRS) {
        int a = ia[i], b = ib[i];
        int ca = lbound(batch, N_NODES, a + 1) - lbound(batch, N_NODES, a);
        int cb = lbound(batch, N_NODES, b + 1) - lbound(batch, N_NODES, b);
        float ua = sums[a] / fmaxf((float)ca, 1.0f);
        float ub = sums[b] / fmaxf((float)cb, 1.0f);
        out_pairs[i] = 1.0f / (1.0f + __expf(-(ub - ua)));
    }
}

// ---------------- launch ----------------

extern "C" void kernel_launch(void* const* d_in, const int* in_sizes, int n_in,
                              void* d_out, int out_size, void* d_ws, size_t ws_size,
                              hipStream_t stream) {
    const float* x     = (const float*)d_in[0];
    const int*   ei    = (const int*)d_in[1];
    const int*   batch = (const int*)d_in[2];
    const int*   idx_a = (const int*)d_in[3];
    const int*   idx_b = (const int*)d_in[4];
    const float* W_in  = (const float*)d_in[5];
    const float* b_in  = (const float*)d_in[6];
    const float* W_h   = (const float*)d_in[7];
    const float* b_h   = (const float*)d_in[8];
    const float* W_out = (const float*)d_in[9];
    const float* b_out = (const float*)d_in[10];
    const float* fc1_w = (const float*)d_in[11];
    const float* fc1_b = (const float*)d_in[12];
    const float* fc2_w = (const float*)d_in[13];
    const float* fc2_b = (const float*)d_in[14];
    const float* fc3_w = (const float*)d_in[15];
    const float* fc3_b = (const float*)d_in[16];

    const int* src = ei;
    const int* dst = ei + N_EDGES;

    char* wsb = (char*)d_ws;
    // zero-region (one memset): degi, sums
    int*   degi     = (int*)wsb;    wsb += N_NODES * 4;
    float* sums     = (float*)wsb;  wsb += N_GRAPHS * 4;
    float* dis      = (float*)wsb;  wsb += N_NODES * 4;
    float* xs       = (float*)wsb;  wsb += (size_t)N_NODES * F_IN * 4;
    unsigned short* h0 = (unsigned short*)wsb;  wsb += (size_t)N_NODES * H * 2;
    unsigned short* h1 = (unsigned short*)wsb;  wsb += (size_t)N_NODES * H * 2;
    int*   offs     = (int*)wsb;    wsb += (N_NODES + 1) * 4;
    int*   chunksum = (int*)wsb;    wsb += NCHUNK * 4;
    int*   chunkbase= (int*)wsb;    wsb += NCHUNK * 4;
    unsigned char* rank = (unsigned char*)wsb;  wsb += N_EDGES;
    wsb = (char*)(((size_t)wsb + 3) & ~(size_t)3);
    unsigned int* csr32 = (unsigned int*)wsb; wsb += (size_t)N_EDGES * 4;

    float* out_pairs = (float*)d_out;
    float* out_util  = out_pairs + N_PAIRS;

    hipMemsetAsync(degi, 0, (N_NODES + N_GRAPHS) * sizeof(int), stream);

    dim3 blk(256);
    k_deg_rank<<<(N_EDGES + 255) / 256, blk, 0, stream>>>(dst, degi, rank);
    k_dis_chunksum<<<NCHUNK, blk, 0, stream>>>(degi, x, dis, xs, chunksum);
    k_scanchunks<<<1, 64, 0, stream>>>(chunksum, chunkbase, offs);
    k_scan<<<NCHUNK, blk, 0, stream>>>(degi, chunkbase, offs);
    k_fill<<<(N_EDGES + 255) / 256, blk, 0, stream>>>(src, dst, rank, offs, csr32);

    // layer 1 fused: agg xs + mm_in, outputs hs (tanh*dis)
    k_layer1<<<(N_NODES + 15) / 16, blk, 0, stream>>>(xs, offs, csr32, dis, W_in, b_in, h0);

    const int gmm_blocks = (N_NODES + 31) / 32;
    // layers 2..4: fused sum+scale+matmul+bias+tanh (depth-2 pipelined)
    k_gmm<<<gmm_blocks, blk, 0, stream>>>(h0, offs, csr32, dis, W_h, b_h, h1, 1);
    k_gmm<<<gmm_blocks, blk, 0, stream>>>(h1, offs, csr32, dis, W_h, b_h, h0, 1);
    k_gmm<<<gmm_blocks, blk, 0, stream>>>(h0, offs, csr32, dis, W_out, b_out, h1, 0);

    // MLP + pool: one lane per node
    k_mlp<<<(N_NODES + 255) / 256, blk, 0, stream>>>(h1, batch, fc1_w, fc1_b, fc2_w,
                                                     fc2_b, fc3_w, fc3_b, sums);
    k_finish<<<(N_GRAPHS + 255) / 256, blk, 0, stream>>>(sums, batch, idx_a, idx_b,
                                                         out_pairs, out_util);
}

// Round 18
// 261.045 us; speedup vs baseline: 3.7055x; 3.7055x over previous
//
#include <hip/hip_runtime.h>
#include <math.h>

#define N_NODES  50000
#define N_EDGES  800000
#define N_GRAPHS 5000
#define N_PAIRS  4096
#define F_IN     9
#define H        64
#define NCHUNK   49   // ceil(50000/1024)
#define WPAD     68   // transposed-weight row stride: 272B = 16B-aligned

__device__ __forceinline__ float fast_tanh(float x) {
    float e = __expf(-2.0f * fabsf(x));
    float t = __fdividef(1.0f - e, 1.0f + e);
    return copysignf(t, x);
}

__device__ __forceinline__ float bf2f(unsigned short u) {
    union { unsigned int i; float f; } v; v.i = ((unsigned int)u) << 16; return v.f;
}
__device__ __forceinline__ unsigned short f2bf(float f) {
    union { float f; unsigned int i; } v; v.f = f;
    unsigned int u = v.i;
    return (unsigned short)((u + 0x7FFFu + ((u >> 16) & 1u)) >> 16);
}

__device__ __forceinline__ int lbound(const int* __restrict__ a, int n, int v) {
    int lo = 0, hi = n;
    while (lo < hi) { int m = (lo + hi) >> 1; if (a[m] < v) lo = m + 1; else hi = m; }
    return lo;
}

// ---------------- degree + per-edge rank (atomic return value IS the rank) --------

__global__ void k_deg_rank(const int* __restrict__ dst, int* __restrict__ degi,
                           unsigned char* __restrict__ rank) {
    int i = blockIdx.x * blockDim.x + threadIdx.x;
    if (i < N_EDGES) rank[i] = (unsigned char)atomicAdd(&degi[dst[i]], 1);
}

// ---------------- dis + xs = x*dis + chunk sums (merged) ----------------

__global__ void k_dis_chunksum(const int* __restrict__ degi, const float* __restrict__ x,
                               float* __restrict__ dis, float* __restrict__ xs,
                               int* __restrict__ chunksum) {
    __shared__ int wsum[4];
    int t = threadIdx.x, lane = t & 63, wi = t >> 6;
    int base_i = blockIdx.x * 1024 + t * 4;
    int s = 0;
#pragma unroll
    for (int k = 0; k < 4; ++k) {
        int i = base_i + k;
        if (i < N_NODES) {
            int dg = degi[i];
            s += dg;
            float d = rsqrtf((float)dg + 1.0f);
            dis[i] = d;
#pragma unroll
            for (int j = 0; j < F_IN; ++j) xs[i * F_IN + j] = x[i * F_IN + j] * d;
        }
    }
    for (int o = 32; o > 0; o >>= 1) s += __shfl_down(s, o, 64);
    if (lane == 0) wsum[wi] = s;
    __syncthreads();
    if (t == 0) chunksum[blockIdx.x] = wsum[0] + wsum[1] + wsum[2] + wsum[3];
}

__global__ void k_scanchunks(const int* __restrict__ chunksum, int* __restrict__ chunkbase,
                             int* __restrict__ off) {
    int lane = threadIdx.x;
    int v = (lane < NCHUNK) ? chunksum[lane] : 0;
    int inc = v;
    for (int o = 1; o < 64; o <<= 1) {
        int u = __shfl_up(inc, o, 64);
        if (lane >= o) inc += u;
    }
    if (lane < NCHUNK) chunkbase[lane] = inc - v;
    if (lane == 0) off[N_NODES] = N_EDGES;
}

__global__ void k_scan(const int* __restrict__ degi, const int* __restrict__ chunkbase,
                       int* __restrict__ off) {
    __shared__ int wsum[4];
    int t = threadIdx.x, lane = t & 63, wi = t >> 6;
    int base_i = blockIdx.x * 1024 + t * 4;
    int v[4];
    int s = 0;
#pragma unroll
    for (int k = 0; k < 4; ++k) {
        int i = base_i + k;
        v[k] = (i < N_NODES) ? degi[i] : 0;
        s += v[k];
    }
    int inc = s;
    for (int o = 1; o < 64; o <<= 1) {
        int u = __shfl_up(inc, o, 64);
        if (lane >= o) inc += u;
    }
    if (lane == 63) wsum[wi] = inc;
    __syncthreads();
    int wbase = 0;
    for (int w = 0; w < 4; ++w) if (w < wi) wbase += wsum[w];
    int ex = chunkbase[blockIdx.x] + wbase + inc - s;
#pragma unroll
    for (int k = 0; k < 4; ++k) {
        int i = base_i + k;
        if (i < N_NODES) off[i] = ex;
        ex += v[k];
    }
}

// CSR entry = u32 src byte-offset (src<<7). pos = off[dst]+rank, no atomic.
__global__ void k_fill(const int* __restrict__ src, const int* __restrict__ dst,
                       const unsigned char* __restrict__ rank,
                       const int* __restrict__ off, unsigned int* __restrict__ csr32) {
    int e = blockIdx.x * blockDim.x + threadIdx.x;
    if (e < N_EDGES) {
        int d = dst[e];
        int pos = off[d] + (int)rank[e];
        csr32[pos] = (unsigned int)(src[e] << 7);
    }
}

// ---------------- layer 1 fused: agg xs (9-wide) -> *dis -> LDS -> mm+tanh*dis -------

__global__ __launch_bounds__(256) void k_layer1(
        const float* __restrict__ xs, const int* __restrict__ off,
        const unsigned int* __restrict__ csr32,
        const float* __restrict__ dis, const float* __restrict__ W,
        const float* __restrict__ b, unsigned short* __restrict__ h) {
    __shared__ float sW[F_IN * H];
    __shared__ float sb[H];
    __shared__ float sax[16][F_IN + 1];   // +1 pad
    __shared__ float sdis[16];
    for (int t = threadIdx.x; t < F_IN * H; t += 256) sW[t] = W[t];
    if (threadIdx.x < H) sb[threadIdx.x] = b[threadIdx.x];

    // phase 1: 16-lane group per node (lanes 0..8 active)
    int g = threadIdx.x >> 4, l = threadIdx.x & 15;
    int node = blockIdx.x * 16 + g;
    if (node < N_NODES && l < F_IN) {
        int beg = off[node], end = off[node + 1];
        float d = dis[node];
        float acc = xs[node * F_IN + l];
        for (int e = beg; e < end; ++e) {
            int s = (int)(csr32[e] >> 7);
            acc += xs[s * F_IN + l];
        }
        sax[g][l] = acc * d;
        if (l == 0) sdis[g] = d;
    }
    __syncthreads();

    // phase 2: 4 rows per wave; output hs = tanh * dis (folded for next layer)
    int wi = threadIdx.x >> 6, j = threadIdx.x & 63;
    for (int r = 0; r < 4; ++r) {
        int row = blockIdx.x * 16 + wi * 4 + r;
        if (row >= N_NODES) break;
        float acc = sb[j];
#pragma unroll
        for (int k = 0; k < F_IN; ++k) acc += sax[wi * 4 + r][k] * sW[k * H + j];
        h[row * H + j] = f2bf(fast_tanh(acc) * sdis[wi * 4 + r]);
    }
}

// ---------------- fused layer: sum(hs) -> *dis -> @W + b -> tanh [*dis] -> bf16 -------
// depth-2 pipeline on u32 entries; inner loop is pure {load, gather, add}.

__global__ __launch_bounds__(256) void k_gmm(
        const unsigned short* __restrict__ hin, const int* __restrict__ off,
        const unsigned int* __restrict__ csr32,
        const float* __restrict__ dis, const float* __restrict__ W,
        const float* __restrict__ b, unsigned short* __restrict__ hout,
        const int fold) {
    __shared__ float sWt[H][WPAD];   // sWt[j][k] = W[k][j]
    __shared__ float sb[H];
    __shared__ float srow[4][H];
    for (int t = threadIdx.x; t < H * H; t += 256) {
        int k = t >> 6, jx = t & 63;
        sWt[jx][k] = W[t];
    }
    if (threadIdx.x < H) sb[threadIdx.x] = b[threadIdx.x];
    __syncthreads();
    int wi = threadIdx.x >> 6, j = threadIdx.x & 63;
    const char* hbase = (const char*)hin + (j << 1);   // per-lane feature offset
    for (int it = 0; it < 8; ++it) {
        int node = blockIdx.x * 32 + wi * 8 + it;
        if (node >= N_NODES) break;
        int beg = off[node], end = off[node + 1];
        float d = dis[node];
        float acc = bf2f(hin[node * H + j]);   // self term: dis*(hs_i + sum)
        int nfull = (end - beg) >> 2;
        int e = beg + (nfull << 2);
        const unsigned int* cp = csr32 + beg;

        if (nfull >= 2) {
            unsigned int a0 = cp[0], a1 = cp[1], a2 = cp[2], a3 = cp[3];
            unsigned int b0 = cp[4], b1 = cp[5], b2 = cp[6], b3 = cp[7];
            float va0 = bf2f(*(const unsigned short*)(hbase + a0));
            float va1 = bf2f(*(const unsigned short*)(hbase + a1));
            float va2 = bf2f(*(const unsigned short*)(hbase + a2));
            float va3 = bf2f(*(const unsigned short*)(hbase + a3));
            for (int bi = 1; bi < nfull - 1; ++bi) {
                float vb0 = bf2f(*(const unsigned short*)(hbase + b0));
                float vb1 = bf2f(*(const unsigned short*)(hbase + b1));
                float vb2 = bf2f(*(const unsigned short*)(hbase + b2));
                float vb3 = bf2f(*(const unsigned short*)(hbase + b3));
                const unsigned int* np = cp + ((bi + 1) << 2);
                unsigned int c0 = np[0], c1 = np[1], c2 = np[2], c3 = np[3];
                acc += (va0 + va1) + (va2 + va3);
                a0 = b0; a1 = b1; a2 = b2; a3 = b3;
                va0 = vb0; va1 = vb1; va2 = vb2; va3 = vb3;
                b0 = c0; b1 = c1; b2 = c2; b3 = c3;
            }
            float vb0 = bf2f(*(const unsigned short*)(hbase + b0));
            float vb1 = bf2f(*(const unsigned short*)(hbase + b1));
            float vb2 = bf2f(*(const unsigned short*)(hbase + b2));
            float vb3 = bf2f(*(const unsigned short*)(hbase + b3));
            acc += (va0 + va1) + (va2 + va3);
            acc += (vb0 + vb1) + (vb2 + vb3);
        } else if (nfull == 1) {
            float v0 = bf2f(*(const unsigned short*)(hbase + cp[0]));
            float v1 = bf2f(*(const unsigned short*)(hbase + cp[1]));
            float v2 = bf2f(*(const unsigned short*)(hbase + cp[2]));
            float v3 = bf2f(*(const unsigned short*)(hbase + cp[3]));
            acc += (v0 + v1) + (v2 + v3);
        }
        for (; e < end; ++e)
            acc += bf2f(*(const unsigned short*)(hbase + csr32[e]));

        srow[wi][j] = acc * d;      // wave-local write then read: in-order per wave
        float a = sb[j];
#pragma unroll
        for (int kb = 0; kb < H; kb += 4) {
            float4 g4 = *(const float4*)&srow[wi][kb];   // uniform-addr broadcast
            float4 w4 = *(const float4*)&sWt[j][kb];     // per-lane b128
            a += g4.x * w4.x + g4.y * w4.y + g4.z * w4.z + g4.w * w4.w;
        }
        float t = fast_tanh(a);
        hout[node * H + j] = f2bf(fold ? t * d : t);
    }
}

// ---------------- fused MLP + graph pool (R14 variant — best measured) ----------------

__global__ __launch_bounds__(256) void k_mlp(
        const unsigned short* __restrict__ h, const int* __restrict__ batch,
        const float* __restrict__ fc1w, const float* __restrict__ fc1b,
        const float* __restrict__ fc2w, const float* __restrict__ fc2b,
        const float* __restrict__ fc3w, const float* __restrict__ fc3b,
        float* __restrict__ sums) {
    __shared__ float s1t[H][WPAD];    // s1t[j][k] = fc1w[k*H+j]
    __shared__ float s2t[32][WPAD];   // s2t[j][k] = fc2w[k*32+j]
    __shared__ float s3[32];
    __shared__ float sb1[H];
    __shared__ float sb2[32];
    __shared__ float srow[4][H];
    __shared__ float s1out[4][H];

    for (int t = threadIdx.x; t < H * H; t += 256) {
        int k = t >> 6, jx = t & 63;
        s1t[jx][k] = fc1w[t];
    }
    for (int t = threadIdx.x; t < H * 32; t += 256) {
        int k = t >> 5, jx = t & 31;
        s2t[jx][k] = fc2w[t];
    }
    if (threadIdx.x < 32) s3[threadIdx.x] = fc3w[threadIdx.x];
    if (threadIdx.x < H)  sb1[threadIdx.x] = fc1b[threadIdx.x];
    if (threadIdx.x < 32) sb2[threadIdx.x] = fc2b[threadIdx.x];
    __syncthreads();

    int wi = threadIdx.x >> 6, j = threadIdx.x & 63;
    int jj = j & 31, kb0 = (j >> 5) << 5;
    float b3 = fc3b[0];

    for (int it = 0; it < 8; ++it) {
        int node = blockIdx.x * 32 + wi * 8 + it;
        if (node >= N_NODES) break;

        srow[wi][j] = bf2f(h[node * H + j]);

        float a1 = sb1[j];
#pragma unroll
        for (int kb = 0; kb < H; kb += 4) {
            float4 g4 = *(const float4*)&srow[wi][kb];
            float4 w4 = *(const float4*)&s1t[j][kb];
            a1 += g4.x * w4.x + g4.y * w4.y + g4.z * w4.z + g4.w * w4.w;
        }
        a1 = fast_tanh(a1);
        s1out[wi][j] = a1;

        float a2 = 0.f;
#pragma unroll
        for (int kb = 0; kb < 32; kb += 4) {
            float4 g4 = *(const float4*)&s1out[wi][kb0 + kb];
            float4 w4 = *(const float4*)&s2t[jj][kb0 + kb];
            a2 += g4.x * w4.x + g4.y * w4.y + g4.z * w4.z + g4.w * w4.w;
        }
        a2 += __shfl_xor(a2, 32);             // combine k-halves
        float val = fast_tanh(a2 + sb2[jj]) * s3[jj];
        for (int o = 16; o > 0; o >>= 1) val += __shfl_xor(val, o);
        if (j == 0) atomicAdd(&sums[batch[node]], val + b3);
    }
}

// ---------------- readout: util + pairs (cnt via binary search, merged) ----------------

__global__ void k_finish(const float* __restrict__ sums, const int* __restrict__ batch,
                         const int* __restrict__ ia, const int* __restrict__ ib,
                         float* __restrict__ out_pairs, float* __restrict__ out_util) {
    int i = blockIdx.x * blockDim.x + threadIdx.x;
    if (i < N_GRAPHS) {
        int c = lbound(batch, N_NODES, i + 1) - lbound(batch, N_NODES, i);
        out_util[i] = sums[i] / fmaxf((float)c, 1.0f);
    }
    if (i < N_PAIRS) {
        int a = ia[i], b = ib[i];
        int ca = lbound(batch, N_NODES, a + 1) - lbound(batch, N_NODES, a);
        int cb = lbound(batch, N_NODES, b + 1) - lbound(batch, N_NODES, b);
        float ua = sums[a] / fmaxf((float)ca, 1.0f);
        float ub = sums[b] / fmaxf((float)cb, 1.0f);
        out_pairs[i] = 1.0f / (1.0f + __expf(-(ub - ua)));
    }
}

// ---------------- launch ----------------

extern "C" void kernel_launch(void* const* d_in, const int* in_sizes, int n_in,
                              void* d_out, int out_size, void* d_ws, size_t ws_size,
                              hipStream_t stream) {
    const float* x     = (const float*)d_in[0];
    const int*   ei    = (const int*)d_in[1];
    const int*   batch = (const int*)d_in[2];
    const int*   idx_a = (const int*)d_in[3];
    const int*   idx_b = (const int*)d_in[4];
    const float* W_in  = (const float*)d_in[5];
    const float* b_in  = (const float*)d_in[6];
    const float* W_h   = (const float*)d_in[7];
    const float* b_h   = (const float*)d_in[8];
    const float* W_out = (const float*)d_in[9];
    const float* b_out = (const float*)d_in[10];
    const float* fc1_w = (const float*)d_in[11];
    const float* fc1_b = (const float*)d_in[12];
    const float* fc2_w = (const float*)d_in[13];
    const float* fc2_b = (const float*)d_in[14];
    const float* fc3_w = (const float*)d_in[15];
    const float* fc3_b = (const float*)d_in[16];

    const int* src = ei;
    const int* dst = ei + N_EDGES;

    char* wsb = (char*)d_ws;
    // zero-region (one memset): degi, sums
    int*   degi     = (int*)wsb;    wsb += N_NODES * 4;
    float* sums     = (float*)wsb;  wsb += N_GRAPHS * 4;
    float* dis      = (float*)wsb;  wsb += N_NODES * 4;
    float* xs       = (float*)wsb;  wsb += (size_t)N_NODES * F_IN * 4;
    unsigned short* h0 = (unsigned short*)wsb;  wsb += (size_t)N_NODES * H * 2;
    unsigned short* h1 = (unsigned short*)wsb;  wsb += (size_t)N_NODES * H * 2;
    int*   offs     = (int*)wsb;    wsb += (N_NODES + 1) * 4;
    int*   chunksum = (int*)wsb;    wsb += NCHUNK * 4;
    int*   chunkbase= (int*)wsb;    wsb += NCHUNK * 4;
    unsigned char* rank = (unsigned char*)wsb;  wsb += N_EDGES;
    wsb = (char*)(((size_t)wsb + 3) & ~(size_t)3);
    unsigned int* csr32 = (unsigned int*)wsb; wsb += (size_t)N_EDGES * 4;

    float* out_pairs = (float*)d_out;
    float* out_util  = out_pairs + N_PAIRS;

    hipMemsetAsync(degi, 0, (N_NODES + N_GRAPHS) * sizeof(int), stream);

    dim3 blk(256);
    k_deg_rank<<<(N_EDGES + 255) / 256, blk, 0, stream>>>(dst, degi, rank);
    k_dis_chunksum<<<NCHUNK, blk, 0, stream>>>(degi, x, dis, xs, chunksum);
    k_scanchunks<<<1, 64, 0, stream>>>(chunksum, chunkbase, offs);
    k_scan<<<NCHUNK, blk, 0, stream>>>(degi, chunkbase, offs);
    k_fill<<<(N_EDGES + 255) / 256, blk, 0, stream>>>(src, dst, rank, offs, csr32);

    // layer 1 fused: agg xs + mm_in, outputs hs (tanh*dis)
    k_layer1<<<(N_NODES + 15) / 16, blk, 0, stream>>>(xs, offs, csr32, dis, W_in, b_in, h0);

    const int gmm_blocks = (N_NODES + 31) / 32;
    // layers 2..4: fused sum+scale+matmul+bias+tanh (depth-2 pipelined)
    k_gmm<<<gmm_blocks, blk, 0, stream>>>(h0, offs, csr32, dis, W_h, b_h, h1, 1);
    k_gmm<<<gmm_blocks, blk, 0, stream>>>(h1, offs, csr32, dis, W_h, b_h, h0, 1);
    k_gmm<<<gmm_blocks, blk, 0, stream>>>(h0, offs, csr32, dis, W_out, b_out, h1, 0);

    // MLP + pool
    k_mlp<<<gmm_blocks, blk, 0, stream>>>(h1, batch, fc1_w, fc1_b, fc2_w, fc2_b,
                                          fc3_w, fc3_b, sums);
    k_finish<<<(N_GRAPHS + 255) / 256, blk, 0, stream>>>(sums, batch, idx_a, idx_b,
                                                         out_pairs, out_util);
}

// Round 19
// 236.054 us; speedup vs baseline: 4.0978x; 1.1059x over previous
//
#include <hip/hip_runtime.h>
#include <math.h>

#define N_NODES  50000
#define N_EDGES  800000
#define N_GRAPHS 5000
#define N_PAIRS  4096
#define F_IN     9
#define H        64
#define NCHUNK   49   // ceil(50000/1024)
#define WPAD     68   // transposed-weight row stride: 272B = 16B-aligned
#define NTILES   3125 // N_NODES / 16

typedef __attribute__((ext_vector_type(8))) short short8v;   // 8 bf16 (4 VGPRs)
typedef __attribute__((ext_vector_type(4))) float f32x4;     // MFMA accumulator

__device__ __forceinline__ float fast_tanh(float x) {
    float e = __expf(-2.0f * fabsf(x));
    float t = __fdividef(1.0f - e, 1.0f + e);
    return copysignf(t, x);
}

__device__ __forceinline__ float bf2f(unsigned short u) {
    union { unsigned int i; float f; } v; v.i = ((unsigned int)u) << 16; return v.f;
}
__device__ __forceinline__ unsigned short f2bf(float f) {
    union { float f; unsigned int i; } v; v.f = f;
    unsigned int u = v.i;
    return (unsigned short)((u + 0x7FFFu + ((u >> 16) & 1u)) >> 16);
}

__device__ __forceinline__ int lbound(const int* __restrict__ a, int n, int v) {
    int lo = 0, hi = n;
    while (lo < hi) { int m = (lo + hi) >> 1; if (a[m] < v) lo = m + 1; else hi = m; }
    return lo;
}

// ---------------- degree + per-edge rank (atomic return value IS the rank) --------

__global__ void k_deg_rank(const int* __restrict__ dst, int* __restrict__ degi,
                           unsigned char* __restrict__ rank) {
    int i = blockIdx.x * blockDim.x + threadIdx.x;
    if (i < N_EDGES) rank[i] = (unsigned char)atomicAdd(&degi[dst[i]], 1);
}

// ---------------- dis + xs = x*dis + chunk sums (merged) ----------------

__global__ void k_dis_chunksum(const int* __restrict__ degi, const float* __restrict__ x,
                               float* __restrict__ dis, float* __restrict__ xs,
                               int* __restrict__ chunksum) {
    __shared__ int wsum[4];
    int t = threadIdx.x, lane = t & 63, wi = t >> 6;
    int base_i = blockIdx.x * 1024 + t * 4;
    int s = 0;
#pragma unroll
    for (int k = 0; k < 4; ++k) {
        int i = base_i + k;
        if (i < N_NODES) {
            int dg = degi[i];
            s += dg;
            float d = rsqrtf((float)dg + 1.0f);
            dis[i] = d;
#pragma unroll
            for (int j = 0; j < F_IN; ++j) xs[i * F_IN + j] = x[i * F_IN + j] * d;
        }
    }
    for (int o = 32; o > 0; o >>= 1) s += __shfl_down(s, o, 64);
    if (lane == 0) wsum[wi] = s;
    __syncthreads();
    if (t == 0) chunksum[blockIdx.x] = wsum[0] + wsum[1] + wsum[2] + wsum[3];
}

__global__ void k_scanchunks(const int* __restrict__ chunksum, int* __restrict__ chunkbase,
                             int* __restrict__ off) {
    int lane = threadIdx.x;
    int v = (lane < NCHUNK) ? chunksum[lane] : 0;
    int inc = v;
    for (int o = 1; o < 64; o <<= 1) {
        int u = __shfl_up(inc, o, 64);
        if (lane >= o) inc += u;
    }
    if (lane < NCHUNK) chunkbase[lane] = inc - v;
    if (lane == 0) off[N_NODES] = N_EDGES;
}

__global__ void k_scan(const int* __restrict__ degi, const int* __restrict__ chunkbase,
                       int* __restrict__ off) {
    __shared__ int wsum[4];
    int t = threadIdx.x, lane = t & 63, wi = t >> 6;
    int base_i = blockIdx.x * 1024 + t * 4;
    int v[4];
    int s = 0;
#pragma unroll
    for (int k = 0; k < 4; ++k) {
        int i = base_i + k;
        v[k] = (i < N_NODES) ? degi[i] : 0;
        s += v[k];
    }
    int inc = s;
    for (int o = 1; o < 64; o <<= 1) {
        int u = __shfl_up(inc, o, 64);
        if (lane >= o) inc += u;
    }
    if (lane == 63) wsum[wi] = inc;
    __syncthreads();
    int wbase = 0;
    for (int w = 0; w < 4; ++w) if (w < wi) wbase += wsum[w];
    int ex = chunkbase[blockIdx.x] + wbase + inc - s;
#pragma unroll
    for (int k = 0; k < 4; ++k) {
        int i = base_i + k;
        if (i < N_NODES) off[i] = ex;
        ex += v[k];
    }
}

// CSR entry = u32 src byte-offset (src<<7). pos = off[dst]+rank, no atomic.
__global__ void k_fill(const int* __restrict__ src, const int* __restrict__ dst,
                       const unsigned char* __restrict__ rank,
                       const int* __restrict__ off, unsigned int* __restrict__ csr32) {
    int e = blockIdx.x * blockDim.x + threadIdx.x;
    if (e < N_EDGES) {
        int d = dst[e];
        int pos = off[d] + (int)rank[e];
        csr32[pos] = (unsigned int)(src[e] << 7);
    }
}

// ---------------- layer 1 fused: agg xs (9-wide) -> *dis -> LDS -> mm+tanh*dis -------

__global__ __launch_bounds__(256) void k_layer1(
        const float* __restrict__ xs, const int* __restrict__ off,
        const unsigned int* __restrict__ csr32,
        const float* __restrict__ dis, const float* __restrict__ W,
        const float* __restrict__ b, unsigned short* __restrict__ h) {
    __shared__ float sW[F_IN * H];
    __shared__ float sb[H];
    __shared__ float sax[16][F_IN + 1];   // +1 pad
    __shared__ float sdis[16];
    for (int t = threadIdx.x; t < F_IN * H; t += 256) sW[t] = W[t];
    if (threadIdx.x < H) sb[threadIdx.x] = b[threadIdx.x];

    // phase 1: 16-lane group per node (lanes 0..8 active)
    int g = threadIdx.x >> 4, l = threadIdx.x & 15;
    int node = blockIdx.x * 16 + g;
    if (node < N_NODES && l < F_IN) {
        int beg = off[node], end = off[node + 1];
        float d = dis[node];
        float acc = xs[node * F_IN + l];
        for (int e = beg; e < end; ++e) {
            int s = (int)(csr32[e] >> 7);
            acc += xs[s * F_IN + l];
        }
        sax[g][l] = acc * d;
        if (l == 0) sdis[g] = d;
    }
    __syncthreads();

    // phase 2: 4 rows per wave; output hs = tanh * dis (folded for next layer)
    int wi = threadIdx.x >> 6, j = threadIdx.x & 63;
    for (int r = 0; r < 4; ++r) {
        int row = blockIdx.x * 16 + wi * 4 + r;
        if (row >= N_NODES) break;
        float acc = sb[j];
#pragma unroll
        for (int k = 0; k < F_IN; ++k) acc += sax[wi * 4 + r][k] * sW[k * H + j];
        h[row * H + j] = f2bf(fast_tanh(acc) * sdis[wi * 4 + r]);
    }
}

// ---------------- fused layer: sum(hs) -> *dis -> @W + b -> tanh [*dis] -> bf16 -------
// depth-2 pipeline on u32 entries; inner loop is pure {load, gather, add}.

__global__ __launch_bounds__(256) void k_gmm(
        const unsigned short* __restrict__ hin, const int* __restrict__ off,
        const unsigned int* __restrict__ csr32,
        const float* __restrict__ dis, const float* __restrict__ W,
        const float* __restrict__ b, unsigned short* __restrict__ hout,
        const int fold) {
    __shared__ float sWt[H][WPAD];   // sWt[j][k] = W[k][j]
    __shared__ float sb[H];
    __shared__ float srow[4][H];
    for (int t = threadIdx.x; t < H * H; t += 256) {
        int k = t >> 6, jx = t & 63;
        sWt[jx][k] = W[t];
    }
    if (threadIdx.x < H) sb[threadIdx.x] = b[threadIdx.x];
    __syncthreads();
    int wi = threadIdx.x >> 6, j = threadIdx.x & 63;
    const char* hbase = (const char*)hin + (j << 1);   // per-lane feature offset
    for (int it = 0; it < 8; ++it) {
        int node = blockIdx.x * 32 + wi * 8 + it;
        if (node >= N_NODES) break;
        int beg = off[node], end = off[node + 1];
        float d = dis[node];
        float acc = bf2f(hin[node * H + j]);   // self term: dis*(hs_i + sum)
        int nfull = (end - beg) >> 2;
        int e = beg + (nfull << 2);
        const unsigned int* cp = csr32 + beg;

        if (nfull >= 2) {
            unsigned int a0 = cp[0], a1 = cp[1], a2 = cp[2], a3 = cp[3];
            unsigned int b0 = cp[4], b1 = cp[5], b2 = cp[6], b3 = cp[7];
            float va0 = bf2f(*(const unsigned short*)(hbase + a0));
            float va1 = bf2f(*(const unsigned short*)(hbase + a1));
            float va2 = bf2f(*(const unsigned short*)(hbase + a2));
            float va3 = bf2f(*(const unsigned short*)(hbase + a3));
            for (int bi = 1; bi < nfull - 1; ++bi) {
                float vb0 = bf2f(*(const unsigned short*)(hbase + b0));
                float vb1 = bf2f(*(const unsigned short*)(hbase + b1));
                float vb2 = bf2f(*(const unsigned short*)(hbase + b2));
                float vb3 = bf2f(*(const unsigned short*)(hbase + b3));
                const unsigned int* np = cp + ((bi + 1) << 2);
                unsigned int c0 = np[0], c1 = np[1], c2 = np[2], c3 = np[3];
                acc += (va0 + va1) + (va2 + va3);
                a0 = b0; a1 = b1; a2 = b2; a3 = b3;
                va0 = vb0; va1 = vb1; va2 = vb2; va3 = vb3;
                b0 = c0; b1 = c1; b2 = c2; b3 = c3;
            }
            float vb0 = bf2f(*(const unsigned short*)(hbase + b0));
            float vb1 = bf2f(*(const unsigned short*)(hbase + b1));
            float vb2 = bf2f(*(const unsigned short*)(hbase + b2));
            float vb3 = bf2f(*(const unsigned short*)(hbase + b3));
            acc += (va0 + va1) + (va2 + va3);
            acc += (vb0 + vb1) + (vb2 + vb3);
        } else if (nfull == 1) {
            float v0 = bf2f(*(const unsigned short*)(hbase + cp[0]));
            float v1 = bf2f(*(const unsigned short*)(hbase + cp[1]));
            float v2 = bf2f(*(const unsigned short*)(hbase + cp[2]));
            float v3 = bf2f(*(const unsigned short*)(hbase + cp[3]));
            acc += (v0 + v1) + (v2 + v3);
        }
        for (; e < end; ++e)
            acc += bf2f(*(const unsigned short*)(hbase + csr32[e]));

        srow[wi][j] = acc * d;      // wave-local write then read: in-order per wave
        float a = sb[j];
#pragma unroll
        for (int kb = 0; kb < H; kb += 4) {
            float4 g4 = *(const float4*)&srow[wi][kb];   // uniform-addr broadcast
            float4 w4 = *(const float4*)&sWt[j][kb];     // per-lane b128
            a += g4.x * w4.x + g4.y * w4.y + g4.z * w4.z + g4.w * w4.w;
        }
        float t = fast_tanh(a);
        hout[node * H + j] = f2bf(fold ? t * d : t);
    }
}

// ---------------- fused MLP + graph pool via MFMA ----------------
// One 16-node tile per wave (50000 = 3125*16). fc1: C(16x64)=A(16x64)@fc1w(64x64)
// as 4 N-tiles x 2 K-steps of mfma_f32_16x16x32_bf16; biases folded into C-init
// (col = lane&15 is lane-constant). tanh -> LDS transpose (16x80-pad, conflict-free
// u16 writes, b128 reads) -> fc2 (2 N-tiles x 2 K) -> tanh -> fc3 dot via 4x shfl_xor.
// A-frag: row = lane&15, k = 8*(lane>>4)+j. B-frag: col = lane&15, k = 8*(lane>>4)+j.
// C/D: col = lane&15, row = 4*(lane>>4)+reg  [guide-verified].

__global__ __launch_bounds__(256) void k_mlp(
        const unsigned short* __restrict__ h, const int* __restrict__ batch,
        const float* __restrict__ fc1w, const float* __restrict__ fc1b,
        const float* __restrict__ fc2w, const float* __restrict__ fc2b,
        const float* __restrict__ fc3w, const float* __restrict__ fc3b,
        float* __restrict__ sums) {
    __shared__ unsigned short sh[4][16][80];   // per-wave transpose tile (pad 64->80)

    int wi = threadIdx.x >> 6;
    int lane = threadIdx.x & 63;
    int lo = lane & 15, hi = lane >> 4;

    int tile = blockIdx.x * 4 + wi;
    if (tile >= NTILES) return;                // no barriers below: safe early-exit
    int nodebase = tile * 16;

    // ---- preload weights as bf16 B-fragments in registers ----
    short8v b1[4][2];                          // fc1: 4 N-tiles x 2 K-halves
#pragma unroll
    for (int nt = 0; nt < 4; ++nt)
#pragma unroll
        for (int kh = 0; kh < 2; ++kh)
#pragma unroll
            for (int j = 0; j < 8; ++j)
                b1[nt][kh][j] = (short)f2bf(fc1w[(kh * 32 + hi * 8 + j) * H + nt * 16 + lo]);
    short8v b2[2][2];                          // fc2: 2 N-tiles x 2 K-halves
#pragma unroll
    for (int nt = 0; nt < 2; ++nt)
#pragma unroll
        for (int kh = 0; kh < 2; ++kh)
#pragma unroll
            for (int j = 0; j < 8; ++j)
                b2[nt][kh][j] = (short)f2bf(fc2w[(kh * 32 + hi * 8 + j) * 32 + nt * 16 + lo]);
    float bias1_0 = fc1b[lo], bias1_1 = fc1b[16 + lo];
    float bias1_2 = fc1b[32 + lo], bias1_3 = fc1b[48 + lo];
    float bias2_0 = fc2b[lo], bias2_1 = fc2b[16 + lo];
    float w3_0 = fc3w[lo], w3_1 = fc3w[16 + lo];
    float b3 = fc3b[0];

    // ---- A-fragments straight from bf16 h ----
    short8v a0 = *(const short8v*)(h + (size_t)(nodebase + lo) * H + hi * 8);
    short8v a1 = *(const short8v*)(h + (size_t)(nodebase + lo) * H + 32 + hi * 8);

    // ---- fc1 ----
    f32x4 acc0 = {bias1_0, bias1_0, bias1_0, bias1_0};
    f32x4 acc1 = {bias1_1, bias1_1, bias1_1, bias1_1};
    f32x4 acc2t = {bias1_2, bias1_2, bias1_2, bias1_2};
    f32x4 acc3 = {bias1_3, bias1_3, bias1_3, bias1_3};
    acc0 = __builtin_amdgcn_mfma_f32_16x16x32_bf16(a0, b1[0][0], acc0, 0, 0, 0);
    acc0 = __builtin_amdgcn_mfma_f32_16x16x32_bf16(a1, b1[0][1], acc0, 0, 0, 0);
    acc1 = __builtin_amdgcn_mfma_f32_16x16x32_bf16(a0, b1[1][0], acc1, 0, 0, 0);
    acc1 = __builtin_amdgcn_mfma_f32_16x16x32_bf16(a1, b1[1][1], acc1, 0, 0, 0);
    acc2t = __builtin_amdgcn_mfma_f32_16x16x32_bf16(a0, b1[2][0], acc2t, 0, 0, 0);
    acc2t = __builtin_amdgcn_mfma_f32_16x16x32_bf16(a1, b1[2][1], acc2t, 0, 0, 0);
    acc3 = __builtin_amdgcn_mfma_f32_16x16x32_bf16(a0, b1[3][0], acc3, 0, 0, 0);
    acc3 = __builtin_amdgcn_mfma_f32_16x16x32_bf16(a1, b1[3][1], acc3, 0, 0, 0);

    // ---- tanh + transpose through LDS (wave-local, in-order) ----
#pragma unroll
    for (int r = 0; r < 4; ++r) {
        int row = hi * 4 + r;
        sh[wi][row][lo]      = f2bf(fast_tanh(acc0[r]));
        sh[wi][row][16 + lo] = f2bf(fast_tanh(acc1[r]));
        sh[wi][row][32 + lo] = f2bf(fast_tanh(acc2t[r]));
        sh[wi][row][48 + lo] = f2bf(fast_tanh(acc3[r]));
    }
    short8v s0 = *(const short8v*)&sh[wi][lo][hi * 8];
    short8v s1 = *(const short8v*)&sh[wi][lo][32 + hi * 8];

    // ---- fc2 ----
    f32x4 c20 = {bias2_0, bias2_0, bias2_0, bias2_0};
    f32x4 c21 = {bias2_1, bias2_1, bias2_1, bias2_1};
    c20 = __builtin_amdgcn_mfma_f32_16x16x32_bf16(s0, b2[0][0], c20, 0, 0, 0);
    c20 = __builtin_amdgcn_mfma_f32_16x16x32_bf16(s1, b2[0][1], c20, 0, 0, 0);
    c21 = __builtin_amdgcn_mfma_f32_16x16x32_bf16(s0, b2[1][0], c21, 0, 0, 0);
    c21 = __builtin_amdgcn_mfma_f32_16x16x32_bf16(s1, b2[1][1], c21, 0, 0, 0);

    // ---- fc3 partials + 16-lane reduce + pool ----
    float p0 = fast_tanh(c20[0]) * w3_0 + fast_tanh(c21[0]) * w3_1;
    float p1 = fast_tanh(c20[1]) * w3_0 + fast_tanh(c21[1]) * w3_1;
    float p2 = fast_tanh(c20[2]) * w3_0 + fast_tanh(c21[2]) * w3_1;
    float p3 = fast_tanh(c20[3]) * w3_0 + fast_tanh(c21[3]) * w3_1;
#pragma unroll
    for (int m = 1; m < 16; m <<= 1) {
        p0 += __shfl_xor(p0, m);
        p1 += __shfl_xor(p1, m);
        p2 += __shfl_xor(p2, m);
        p3 += __shfl_xor(p3, m);
    }
    if (lo == 0) {
        int nb = nodebase + hi * 4;
        atomicAdd(&sums[batch[nb]],     p0 + b3);
        atomicAdd(&sums[batch[nb + 1]], p1 + b3);
        atomicAdd(&sums[batch[nb + 2]], p2 + b3);
        atomicAdd(&sums[batch[nb + 3]], p3 + b3);
    }
}

// ---------------- readout: util + pairs (cnt via binary search, merged) ----------------

__global__ void k_finish(const float* __restrict__ sums, const int* __restrict__ batch,
                         const int* __restrict__ ia, const int* __restrict__ ib,
                         float* __restrict__ out_pairs, float* __restrict__ out_util) {
    int i = blockIdx.x * blockDim.x + threadIdx.x;
    if (i < N_GRAPHS) {
        int c = lbound(batch, N_NODES, i + 1) - lbound(batch, N_NODES, i);
        out_util[i] = sums[i] / fmaxf((float)c, 1.0f);
    }
    if (i < N_PAIRS) {
        int a = ia[i], b = ib[i];
        int ca = lbound(batch, N_NODES, a + 1) - lbound(batch, N_NODES, a);
        int cb = lbound(batch, N_NODES, b + 1) - lbound(batch, N_NODES, b);
        float ua = sums[a] / fmaxf((float)ca, 1.0f);
        float ub = sums[b] / fmaxf((float)cb, 1.0f);
        out_pairs[i] = 1.0f / (1.0f + __expf(-(ub - ua)));
    }
}

// ---------------- launch ----------------

extern "C" void kernel_launch(void* const* d_in, const int* in_sizes, int n_in,
                              void* d_out, int out_size, void* d_ws, size_t ws_size,
                              hipStream_t stream) {
    const float* x     = (const float*)d_in[0];
    const int*   ei    = (const int*)d_in[1];
    const int*   batch = (const int*)d_in[2];
    const int*   idx_a = (const int*)d_in[3];
    const int*   idx_b = (const int*)d_in[4];
    const float* W_in  = (const float*)d_in[5];
    const float* b_in  = (const float*)d_in[6];
    const float* W_h   = (const float*)d_in[7];
    const float* b_h   = (const float*)d_in[8];
    const float* W_out = (const float*)d_in[9];
    const float* b_out = (const float*)d_in[10];
    const float* fc1_w = (const float*)d_in[11];
    const float* fc1_b = (const float*)d_in[12];
    const float* fc2_w = (const float*)d_in[13];
    const float* fc2_b = (const float*)d_in[14];
    const float* fc3_w = (const float*)d_in[15];
    const float* fc3_b = (const float*)d_in[16];

    const int* src = ei;
    const int* dst = ei + N_EDGES;

    char* wsb = (char*)d_ws;
    // zero-region (one memset): degi, sums
    int*   degi     = (int*)wsb;    wsb += N_NODES * 4;
    float* sums     = (float*)wsb;  wsb += N_GRAPHS * 4;
    float* dis      = (float*)wsb;  wsb += N_NODES * 4;
    float* xs       = (float*)wsb;  wsb += (size_t)N_NODES * F_IN * 4;
    unsigned short* h0 = (unsigned short*)wsb;  wsb += (size_t)N_NODES * H * 2;
    unsigned short* h1 = (unsigned short*)wsb;  wsb += (size_t)N_NODES * H * 2;
    int*   offs     = (int*)wsb;    wsb += (N_NODES + 1) * 4;
    int*   chunksum = (int*)wsb;    wsb += NCHUNK * 4;
    int*   chunkbase= (int*)wsb;    wsb += NCHUNK * 4;
    unsigned char* rank = (unsigned char*)wsb;  wsb += N_EDGES;
    wsb = (char*)(((size_t)wsb + 3) & ~(size_t)3);
    unsigned int* csr32 = (unsigned int*)wsb; wsb += (size_t)N_EDGES * 4;

    float* out_pairs = (float*)d_out;
    float* out_util  = out_pairs + N_PAIRS;

    hipMemsetAsync(degi, 0, (N_NODES + N_GRAPHS) * sizeof(int), stream);

    dim3 blk(256);
    k_deg_rank<<<(N_EDGES + 255) / 256, blk, 0, stream>>>(dst, degi, rank);
    k_dis_chunksum<<<NCHUNK, blk, 0, stream>>>(degi, x, dis, xs, chunksum);
    k_scanchunks<<<1, 64, 0, stream>>>(chunksum, chunkbase, offs);
    k_scan<<<NCHUNK, blk, 0, stream>>>(degi, chunkbase, offs);
    k_fill<<<(N_EDGES + 255) / 256, blk, 0, stream>>>(src, dst, rank, offs, csr32);

    // layer 1 fused: agg xs + mm_in, outputs hs (tanh*dis)
    k_layer1<<<(N_NODES + 15) / 16, blk, 0, stream>>>(xs, offs, csr32, dis, W_in, b_in, h0);

    const int gmm_blocks = (N_NODES + 31) / 32;
    // layers 2..4: fused sum+scale+matmul+bias+tanh (depth-2 pipelined)
    k_gmm<<<gmm_blocks, blk, 0, stream>>>(h0, offs, csr32, dis, W_h, b_h, h1, 1);
    k_gmm<<<gmm_blocks, blk, 0, stream>>>(h1, offs, csr32, dis, W_h, b_h, h0, 1);
    k_gmm<<<gmm_blocks, blk, 0, stream>>>(h0, offs, csr32, dis, W_out, b_out, h1, 0);

    // MLP + pool via MFMA: one 16-node tile per wave
    k_mlp<<<(NTILES + 3) / 4, blk, 0, stream>>>(h1, batch, fc1_w, fc1_b, fc2_w, fc2_b,
                                                fc3_w, fc3_b, sums);
    k_finish<<<(N_GRAPHS + 255) / 256, blk, 0, stream>>>(sums, batch, idx_a, idx_b,
                                                         out_pairs, out_util);
}

// Round 20
// 226.786 us; speedup vs baseline: 4.2653x; 1.0409x over previous
//
#include <hip/hip_runtime.h>
#include <math.h>

#define N_NODES  50000
#define N_EDGES  800000
#define N_GRAPHS 5000
#define N_PAIRS  4096
#define F_IN     9
#define H        64
#define NCHUNK   49   // ceil(50000/1024)
#define WPAD     68   // transposed-weight row stride: 272B = 16B-aligned
#define NTILES   3125 // N_NODES / 16

typedef __attribute__((ext_vector_type(8))) short short8v;   // 8 bf16 (4 VGPRs)
typedef __attribute__((ext_vector_type(4))) float f32x4;     // MFMA accumulator

__device__ __forceinline__ float fast_tanh(float x) {
    float e = __expf(-2.0f * fabsf(x));
    float t = __fdividef(1.0f - e, 1.0f + e);
    return copysignf(t, x);
}

__device__ __forceinline__ float bf2f(unsigned short u) {
    union { unsigned int i; float f; } v; v.i = ((unsigned int)u) << 16; return v.f;
}
__device__ __forceinline__ unsigned short f2bf(float f) {
    union { float f; unsigned int i; } v; v.f = f;
    unsigned int u = v.i;
    return (unsigned short)((u + 0x7FFFu + ((u >> 16) & 1u)) >> 16);
}

__device__ __forceinline__ int lbound(const int* __restrict__ a, int n, int v) {
    int lo = 0, hi = n;
    while (lo < hi) { int m = (lo + hi) >> 1; if (a[m] < v) lo = m + 1; else hi = m; }
    return lo;
}

// ---------------- degree + per-edge rank (atomic return value IS the rank) --------

__global__ void k_deg_rank(const int* __restrict__ dst, int* __restrict__ degi,
                           unsigned char* __restrict__ rank) {
    int i = blockIdx.x * blockDim.x + threadIdx.x;
    if (i < N_EDGES) rank[i] = (unsigned char)atomicAdd(&degi[dst[i]], 1);
}

// ---------------- dis + xs = x*dis + chunk sums (merged) ----------------

__global__ void k_dis_chunksum(const int* __restrict__ degi, const float* __restrict__ x,
                               float* __restrict__ dis, float* __restrict__ xs,
                               int* __restrict__ chunksum) {
    __shared__ int wsum[4];
    int t = threadIdx.x, lane = t & 63, wi = t >> 6;
    int base_i = blockIdx.x * 1024 + t * 4;
    int s = 0;
#pragma unroll
    for (int k = 0; k < 4; ++k) {
        int i = base_i + k;
        if (i < N_NODES) {
            int dg = degi[i];
            s += dg;
            float d = rsqrtf((float)dg + 1.0f);
            dis[i] = d;
#pragma unroll
            for (int j = 0; j < F_IN; ++j) xs[i * F_IN + j] = x[i * F_IN + j] * d;
        }
    }
    for (int o = 32; o > 0; o >>= 1) s += __shfl_down(s, o, 64);
    if (lane == 0) wsum[wi] = s;
    __syncthreads();
    if (t == 0) chunksum[blockIdx.x] = wsum[0] + wsum[1] + wsum[2] + wsum[3];
}

__global__ void k_scanchunks(const int* __restrict__ chunksum, int* __restrict__ chunkbase,
                             int* __restrict__ off) {
    int lane = threadIdx.x;
    int v = (lane < NCHUNK) ? chunksum[lane] : 0;
    int inc = v;
    for (int o = 1; o < 64; o <<= 1) {
        int u = __shfl_up(inc, o, 64);
        if (lane >= o) inc += u;
    }
    if (lane < NCHUNK) chunkbase[lane] = inc - v;
    if (lane == 0) off[N_NODES] = N_EDGES;
}

__global__ void k_scan(const int* __restrict__ degi, const int* __restrict__ chunkbase,
                       int* __restrict__ off) {
    __shared__ int wsum[4];
    int t = threadIdx.x, lane = t & 63, wi = t >> 6;
    int base_i = blockIdx.x * 1024 + t * 4;
    int v[4];
    int s = 0;
#pragma unroll
    for (int k = 0; k < 4; ++k) {
        int i = base_i + k;
        v[k] = (i < N_NODES) ? degi[i] : 0;
        s += v[k];
    }
    int inc = s;
    for (int o = 1; o < 64; o <<= 1) {
        int u = __shfl_up(inc, o, 64);
        if (lane >= o) inc += u;
    }
    if (lane == 63) wsum[wi] = inc;
    __syncthreads();
    int wbase = 0;
    for (int w = 0; w < 4; ++w) if (w < wi) wbase += wsum[w];
    int ex = chunkbase[blockIdx.x] + wbase + inc - s;
#pragma unroll
    for (int k = 0; k < 4; ++k) {
        int i = base_i + k;
        if (i < N_NODES) off[i] = ex;
        ex += v[k];
    }
}

// CSR entry = u32 src byte-offset (src<<7). pos = off[dst]+rank, no atomic.
__global__ void k_fill(const int* __restrict__ src, const int* __restrict__ dst,
                       const unsigned char* __restrict__ rank,
                       const int* __restrict__ off, unsigned int* __restrict__ csr32) {
    int e = blockIdx.x * blockDim.x + threadIdx.x;
    if (e < N_EDGES) {
        int d = dst[e];
        int pos = off[d] + (int)rank[e];
        csr32[pos] = (unsigned int)(src[e] << 7);
    }
}

// ---------------- layer 1 fused: agg xs (9-wide) -> *dis -> LDS -> mm+tanh*dis -------
// phase-1 edge loop: 4-edge batches, depth-2 pipelined (entries one batch ahead).

__global__ __launch_bounds__(256) void k_layer1(
        const float* __restrict__ xs, const int* __restrict__ off,
        const unsigned int* __restrict__ csr32,
        const float* __restrict__ dis, const float* __restrict__ W,
        const float* __restrict__ b, unsigned short* __restrict__ h) {
    __shared__ float sW[F_IN * H];
    __shared__ float sb[H];
    __shared__ float sax[16][F_IN + 1];   // +1 pad
    __shared__ float sdis[16];
    for (int t = threadIdx.x; t < F_IN * H; t += 256) sW[t] = W[t];
    if (threadIdx.x < H) sb[threadIdx.x] = b[threadIdx.x];

    // phase 1: 16-lane group per node (lanes 0..8 active)
    int g = threadIdx.x >> 4, l = threadIdx.x & 15;
    int node = blockIdx.x * 16 + g;
    if (node < N_NODES && l < F_IN) {
        int beg = off[node], end = off[node + 1];
        float d = dis[node];
        float acc = xs[node * F_IN + l];
        int nfull = (end - beg) >> 2;
        int e = beg + (nfull << 2);
        const unsigned int* cp = csr32 + beg;
        if (nfull >= 2) {
            unsigned int a0 = cp[0], a1 = cp[1], a2 = cp[2], a3 = cp[3];
            unsigned int b0 = cp[4], b1 = cp[5], b2 = cp[6], b3 = cp[7];
            float va0 = xs[(a0 >> 7) * F_IN + l], va1 = xs[(a1 >> 7) * F_IN + l];
            float va2 = xs[(a2 >> 7) * F_IN + l], va3 = xs[(a3 >> 7) * F_IN + l];
            for (int bi = 1; bi < nfull - 1; ++bi) {
                float vb0 = xs[(b0 >> 7) * F_IN + l], vb1 = xs[(b1 >> 7) * F_IN + l];
                float vb2 = xs[(b2 >> 7) * F_IN + l], vb3 = xs[(b3 >> 7) * F_IN + l];
                const unsigned int* np = cp + ((bi + 1) << 2);
                unsigned int c0 = np[0], c1 = np[1], c2 = np[2], c3 = np[3];
                acc += (va0 + va1) + (va2 + va3);
                va0 = vb0; va1 = vb1; va2 = vb2; va3 = vb3;
                b0 = c0; b1 = c1; b2 = c2; b3 = c3;
            }
            float vb0 = xs[(b0 >> 7) * F_IN + l], vb1 = xs[(b1 >> 7) * F_IN + l];
            float vb2 = xs[(b2 >> 7) * F_IN + l], vb3 = xs[(b3 >> 7) * F_IN + l];
            acc += (va0 + va1) + (va2 + va3);
            acc += (vb0 + vb1) + (vb2 + vb3);
        } else if (nfull == 1) {
            acc += (xs[(cp[0] >> 7) * F_IN + l] + xs[(cp[1] >> 7) * F_IN + l])
                 + (xs[(cp[2] >> 7) * F_IN + l] + xs[(cp[3] >> 7) * F_IN + l]);
        }
        for (; e < end; ++e) acc += xs[(csr32[e] >> 7) * F_IN + l];
        sax[g][l] = acc * d;
        if (l == 0) sdis[g] = d;
    }
    __syncthreads();

    // phase 2: 4 rows per wave; output hs = tanh * dis (folded for next layer)
    int wi = threadIdx.x >> 6, j = threadIdx.x & 63;
    for (int r = 0; r < 4; ++r) {
        int row = blockIdx.x * 16 + wi * 4 + r;
        if (row >= N_NODES) break;
        float acc = sb[j];
#pragma unroll
        for (int k = 0; k < F_IN; ++k) acc += sax[wi * 4 + r][k] * sW[k * H + j];
        h[row * H + j] = f2bf(fast_tanh(acc) * sdis[wi * 4 + r]);
    }
}

// ---------------- fused layer: sum(hs) -> *dis -> @W + b -> tanh [*dis] -> bf16 -------
// depth-3 pipeline on u32 entries: 12 entries + 8 gathers in flight per wave.

__global__ __launch_bounds__(256) void k_gmm(
        const unsigned short* __restrict__ hin, const int* __restrict__ off,
        const unsigned int* __restrict__ csr32,
        const float* __restrict__ dis, const float* __restrict__ W,
        const float* __restrict__ b, unsigned short* __restrict__ hout,
        const int fold) {
    __shared__ float sWt[H][WPAD];   // sWt[j][k] = W[k][j]
    __shared__ float sb[H];
    __shared__ float srow[4][H];
    for (int t = threadIdx.x; t < H * H; t += 256) {
        int k = t >> 6, jx = t & 63;
        sWt[jx][k] = W[t];
    }
    if (threadIdx.x < H) sb[threadIdx.x] = b[threadIdx.x];
    __syncthreads();
    int wi = threadIdx.x >> 6, j = threadIdx.x & 63;
    const char* hbase = (const char*)hin + (j << 1);   // per-lane feature offset
    for (int it = 0; it < 8; ++it) {
        int node = blockIdx.x * 32 + wi * 8 + it;
        if (node >= N_NODES) break;
        int beg = off[node], end = off[node + 1];
        float d = dis[node];
        float acc = bf2f(hin[node * H + j]);   // self term: dis*(hs_i + sum)
        int nfull = (end - beg) >> 2;
        int e = beg + (nfull << 2);
        const unsigned int* cp = csr32 + beg;

        if (nfull >= 3) {
            unsigned int a0 = cp[0], a1 = cp[1], a2 = cp[2],  a3 = cp[3];
            unsigned int b0 = cp[4], b1 = cp[5], b2 = cp[6],  b3 = cp[7];
            unsigned int g0 = cp[8], g1 = cp[9], g2 = cp[10], g3 = cp[11];
            float va0 = bf2f(*(const unsigned short*)(hbase + a0));
            float va1 = bf2f(*(const unsigned short*)(hbase + a1));
            float va2 = bf2f(*(const unsigned short*)(hbase + a2));
            float va3 = bf2f(*(const unsigned short*)(hbase + a3));
            float vb0 = bf2f(*(const unsigned short*)(hbase + b0));
            float vb1 = bf2f(*(const unsigned short*)(hbase + b1));
            float vb2 = bf2f(*(const unsigned short*)(hbase + b2));
            float vb3 = bf2f(*(const unsigned short*)(hbase + b3));
            for (int bi = 2; bi < nfull - 1; ++bi) {
                // gathers for gen c (entries prefetched one iteration ago)
                float vc0 = bf2f(*(const unsigned short*)(hbase + g0));
                float vc1 = bf2f(*(const unsigned short*)(hbase + g1));
                float vc2 = bf2f(*(const unsigned short*)(hbase + g2));
                float vc3 = bf2f(*(const unsigned short*)(hbase + g3));
                // prefetch entries for gen d (bi+1 <= nfull-1: in bounds)
                const unsigned int* np = cp + ((bi + 1) << 2);
                unsigned int d0 = np[0], d1 = np[1], d2 = np[2], d3 = np[3];
                // retire gen a (its gathers were issued two iterations ago)
                acc += (va0 + va1) + (va2 + va3);
                va0 = vb0; va1 = vb1; va2 = vb2; va3 = vb3;
                vb0 = vc0; vb1 = vc1; vb2 = vc2; vb3 = vc3;
                g0 = d0; g1 = d1; g2 = d2; g3 = d3;
            }
            float vc0 = bf2f(*(const unsigned short*)(hbase + g0));
            float vc1 = bf2f(*(const unsigned short*)(hbase + g1));
            float vc2 = bf2f(*(const unsigned short*)(hbase + g2));
            float vc3 = bf2f(*(const unsigned short*)(hbase + g3));
            acc += (va0 + va1) + (va2 + va3);
            acc += (vb0 + vb1) + (vb2 + vb3);
            acc += (vc0 + vc1) + (vc2 + vc3);
        } else if (nfull == 2) {
            unsigned int a0 = cp[0], a1 = cp[1], a2 = cp[2], a3 = cp[3];
            unsigned int b0 = cp[4], b1 = cp[5], b2 = cp[6], b3 = cp[7];
            float v0 = bf2f(*(const unsigned short*)(hbase + a0));
            float v1 = bf2f(*(const unsigned short*)(hbase + a1));
            float v2 = bf2f(*(const unsigned short*)(hbase + a2));
            float v3 = bf2f(*(const unsigned short*)(hbase + a3));
            float v4 = bf2f(*(const unsigned short*)(hbase + b0));
            float v5 = bf2f(*(const unsigned short*)(hbase + b1));
            float v6 = bf2f(*(const unsigned short*)(hbase + b2));
            float v7 = bf2f(*(const unsigned short*)(hbase + b3));
            acc += ((v0 + v1) + (v2 + v3)) + ((v4 + v5) + (v6 + v7));
        } else if (nfull == 1) {
            float v0 = bf2f(*(const unsigned short*)(hbase + cp[0]));
            float v1 = bf2f(*(const unsigned short*)(hbase + cp[1]));
            float v2 = bf2f(*(const unsigned short*)(hbase + cp[2]));
            float v3 = bf2f(*(const unsigned short*)(hbase + cp[3]));
            acc += (v0 + v1) + (v2 + v3);
        }
        for (; e < end; ++e)
            acc += bf2f(*(const unsigned short*)(hbase + csr32[e]));

        srow[wi][j] = acc * d;      // wave-local write then read: in-order per wave
        float a = sb[j];
#pragma unroll
        for (int kb = 0; kb < H; kb += 4) {
            float4 g4 = *(const float4*)&srow[wi][kb];   // uniform-addr broadcast
            float4 w4 = *(const float4*)&sWt[j][kb];     // per-lane b128
            a += g4.x * w4.x + g4.y * w4.y + g4.z * w4.z + g4.w * w4.w;
        }
        float t = fast_tanh(a);
        hout[node * H + j] = f2bf(fold ? t * d : t);
    }
}

// ---------------- fused MLP + graph pool via MFMA (R19, unchanged) ----------------

__global__ __launch_bounds__(256) void k_mlp(
        const unsigned short* __restrict__ h, const int* __restrict__ batch,
        const float* __restrict__ fc1w, const float* __restrict__ fc1b,
        const float* __restrict__ fc2w, const float* __restrict__ fc2b,
        const float* __restrict__ fc3w, const float* __restrict__ fc3b,
        float* __restrict__ sums) {
    __shared__ unsigned short sh[4][16][80];   // per-wave transpose tile (pad 64->80)

    int wi = threadIdx.x >> 6;
    int lane = threadIdx.x & 63;
    int lo = lane & 15, hi = lane >> 4;

    int tile = blockIdx.x * 4 + wi;
    if (tile >= NTILES) return;                // no barriers below: safe early-exit
    int nodebase = tile * 16;

    short8v b1[4][2];                          // fc1: 4 N-tiles x 2 K-halves
#pragma unroll
    for (int nt = 0; nt < 4; ++nt)
#pragma unroll
        for (int kh = 0; kh < 2; ++kh)
#pragma unroll
            for (int j = 0; j < 8; ++j)
                b1[nt][kh][j] = (short)f2bf(fc1w[(kh * 32 + hi * 8 + j) * H + nt * 16 + lo]);
    short8v b2[2][2];                          // fc2: 2 N-tiles x 2 K-halves
#pragma unroll
    for (int nt = 0; nt < 2; ++nt)
#pragma unroll
        for (int kh = 0; kh < 2; ++kh)
#pragma unroll
            for (int j = 0; j < 8; ++j)
                b2[nt][kh][j] = (short)f2bf(fc2w[(kh * 32 + hi * 8 + j) * 32 + nt * 16 + lo]);
    float bias1_0 = fc1b[lo], bias1_1 = fc1b[16 + lo];
    float bias1_2 = fc1b[32 + lo], bias1_3 = fc1b[48 + lo];
    float bias2_0 = fc2b[lo], bias2_1 = fc2b[16 + lo];
    float w3_0 = fc3w[lo], w3_1 = fc3w[16 + lo];
    float b3 = fc3b[0];

    short8v a0 = *(const short8v*)(h + (size_t)(nodebase + lo) * H + hi * 8);
    short8v a1 = *(const short8v*)(h + (size_t)(nodebase + lo) * H + 32 + hi * 8);

    f32x4 acc0 = {bias1_0, bias1_0, bias1_0, bias1_0};
    f32x4 acc1 = {bias1_1, bias1_1, bias1_1, bias1_1};
    f32x4 acc2t = {bias1_2, bias1_2, bias1_2, bias1_2};
    f32x4 acc3 = {bias1_3, bias1_3, bias1_3, bias1_3};
    acc0 = __builtin_amdgcn_mfma_f32_16x16x32_bf16(a0, b1[0][0], acc0, 0, 0, 0);
    acc0 = __builtin_amdgcn_mfma_f32_16x16x32_bf16(a1, b1[0][1], acc0, 0, 0, 0);
    acc1 = __builtin_amdgcn_mfma_f32_16x16x32_bf16(a0, b1[1][0], acc1, 0, 0, 0);
    acc1 = __builtin_amdgcn_mfma_f32_16x16x32_bf16(a1, b1[1][1], acc1, 0, 0, 0);
    acc2t = __builtin_amdgcn_mfma_f32_16x16x32_bf16(a0, b1[2][0], acc2t, 0, 0, 0);
    acc2t = __builtin_amdgcn_mfma_f32_16x16x32_bf16(a1, b1[2][1], acc2t, 0, 0, 0);
    acc3 = __builtin_amdgcn_mfma_f32_16x16x32_bf16(a0, b1[3][0], acc3, 0, 0, 0);
    acc3 = __builtin_amdgcn_mfma_f32_16x16x32_bf16(a1, b1[3][1], acc3, 0, 0, 0);

#pragma unroll
    for (int r = 0; r < 4; ++r) {
        int row = hi * 4 + r;
        sh[wi][row][lo]      = f2bf(fast_tanh(acc0[r]));
        sh[wi][row][16 + lo] = f2bf(fast_tanh(acc1[r]));
        sh[wi][row][32 + lo] = f2bf(fast_tanh(acc2t[r]));
        sh[wi][row][48 + lo] = f2bf(fast_tanh(acc3[r]));
    }
    short8v s0 = *(const short8v*)&sh[wi][lo][hi * 8];
    short8v s1 = *(const short8v*)&sh[wi][lo][32 + hi * 8];

    f32x4 c20 = {bias2_0, bias2_0, bias2_0, bias2_0};
    f32x4 c21 = {bias2_1, bias2_1, bias2_1, bias2_1};
    c20 = __builtin_amdgcn_mfma_f32_16x16x32_bf16(s0, b2[0][0], c20, 0, 0, 0);
    c20 = __builtin_amdgcn_mfma_f32_16x16x32_bf16(s1, b2[0][1], c20, 0, 0, 0);
    c21 = __builtin_amdgcn_mfma_f32_16x16x32_bf16(s0, b2[1][0], c21, 0, 0, 0);
    c21 = __builtin_amdgcn_mfma_f32_16x16x32_bf16(s1, b2[1][1], c21, 0, 0, 0);

    float p0 = fast_tanh(c20[0]) * w3_0 + fast_tanh(c21[0]) * w3_1;
    float p1 = fast_tanh(c20[1]) * w3_0 + fast_tanh(c21[1]) * w3_1;
    float p2 = fast_tanh(c20[2]) * w3_0 + fast_tanh(c21[2]) * w3_1;
    float p3 = fast_tanh(c20[3]) * w3_0 + fast_tanh(c21[3]) * w3_1;
#pragma unroll
    for (int m = 1; m < 16; m <<= 1) {
        p0 += __shfl_xor(p0, m);
        p1 += __shfl_xor(p1, m);
        p2 += __shfl_xor(p2, m);
        p3 += __shfl_xor(p3, m);
    }
    if (lo == 0) {
        int nb = nodebase + hi * 4;
        atomicAdd(&sums[batch[nb]],     p0 + b3);
        atomicAdd(&sums[batch[nb + 1]], p1 + b3);
        atomicAdd(&sums[batch[nb + 2]], p2 + b3);
        atomicAdd(&sums[batch[nb + 3]], p3 + b3);
    }
}

// ---------------- readout: util + pairs (cnt via binary search, merged) ----------------

__global__ void k_finish(const float* __restrict__ sums, const int* __restrict__ batch,
                         const int* __restrict__ ia, const int* __restrict__ ib,
                         float* __restrict__ out_pairs, float* __restrict__ out_util) {
    int i = blockIdx.x * blockDim.x + threadIdx.x;
    if (i < N_GRAPHS) {
        int c = lbound(batch, N_NODES, i + 1) - lbound(batch, N_NODES, i);
        out_util[i] = sums[i] / fmaxf((float)c, 1.0f);
    }
    if (i < N_PAIRS) {
        int a = ia[i], b = ib[i];
        int ca = lbound(batch, N_NODES, a + 1) - lbound(batch, N_NODES, a);
        int cb = lbound(batch, N_NODES, b + 1) - lbound(batch, N_NODES, b);
        float ua = sums[a] / fmaxf((float)ca, 1.0f);
        float ub = sums[b] / fmaxf((float)cb, 1.0f);
        out_pairs[i] = 1.0f / (1.0f + __expf(-(ub - ua)));
    }
}

// ---------------- launch ----------------

extern "C" void kernel_launch(void* const* d_in, const int* in_sizes, int n_in,
                              void* d_out, int out_size, void* d_ws, size_t ws_size,
                              hipStream_t stream) {
    const float* x     = (const float*)d_in[0];
    const int*   ei    = (const int*)d_in[1];
    const int*   batch = (const int*)d_in[2];
    const int*   idx_a = (const int*)d_in[3];
    const int*   idx_b = (const int*)d_in[4];
    const float* W_in  = (const float*)d_in[5];
    const float* b_in  = (const float*)d_in[6];
    const float* W_h   = (const float*)d_in[7];
    const float* b_h   = (const float*)d_in[8];
    const float* W_out = (const float*)d_in[9];
    const float* b_out = (const float*)d_in[10];
    const float* fc1_w = (const float*)d_in[11];
    const float* fc1_b = (const float*)d_in[12];
    const float* fc2_w = (const float*)d_in[13];
    const float* fc2_b = (const float*)d_in[14];
    const float* fc3_w = (const float*)d_in[15];
    const float* fc3_b = (const float*)d_in[16];

    const int* src = ei;
    const int* dst = ei + N_EDGES;

    char* wsb = (char*)d_ws;
    // zero-region (one memset): degi, sums
    int*   degi     = (int*)wsb;    wsb += N_NODES * 4;
    float* sums     = (float*)wsb;  wsb += N_GRAPHS * 4;
    float* dis      = (float*)wsb;  wsb += N_NODES * 4;
    float* xs       = (float*)wsb;  wsb += (size_t)N_NODES * F_IN * 4;
    unsigned short* h0 = (unsigned short*)wsb;  wsb += (size_t)N_NODES * H * 2;
    unsigned short* h1 = (unsigned short*)wsb;  wsb += (size_t)N_NODES * H * 2;
    int*   offs     = (int*)wsb;    wsb += (N_NODES + 1) * 4;
    int*   chunksum = (int*)wsb;    wsb += NCHUNK * 4;
    int*   chunkbase= (int*)wsb;    wsb += NCHUNK * 4;
    unsigned char* rank = (unsigned char*)wsb;  wsb += N_EDGES;
    wsb = (char*)(((size_t)wsb + 3) & ~(size_t)3);
    unsigned int* csr32 = (unsigned int*)wsb; wsb += (size_t)N_EDGES * 4 + 64;

    float* out_pairs = (float*)d_out;
    float* out_util  = out_pairs + N_PAIRS;

    hipMemsetAsync(degi, 0, (N_NODES + N_GRAPHS) * sizeof(int), stream);

    dim3 blk(256);
    k_deg_rank<<<(N_EDGES + 255) / 256, blk, 0, stream>>>(dst, degi, rank);
    k_dis_chunksum<<<NCHUNK, blk, 0, stream>>>(degi, x, dis, xs, chunksum);
    k_scanchunks<<<1, 64, 0, stream>>>(chunksum, chunkbase, offs);
    k_scan<<<NCHUNK, blk, 0, stream>>>(degi, chunkbase, offs);
    k_fill<<<(N_EDGES + 255) / 256, blk, 0, stream>>>(src, dst, rank, offs, csr32);

    // layer 1 fused: agg xs + mm_in, outputs hs (tanh*dis)
    k_layer1<<<(N_NODES + 15) / 16, blk, 0, stream>>>(xs, offs, csr32, dis, W_in, b_in, h0);

    const int gmm_blocks = (N_NODES + 31) / 32;
    // layers 2..4: fused sum+scale+matmul+bias+tanh (depth-3 pipelined)
    k_gmm<<<gmm_blocks, blk, 0, stream>>>(h0, offs, csr32, dis, W_h, b_h, h1, 1);
    k_gmm<<<gmm_blocks, blk, 0, stream>>>(h1, offs, csr32, dis, W_h, b_h, h0, 1);
    k_gmm<<<gmm_blocks, blk, 0, stream>>>(h0, offs, csr32, dis, W_out, b_out, h1, 0);

    // MLP + pool via MFMA: one 16-node tile per wave
    k_mlp<<<(NTILES + 3) / 4, blk, 0, stream>>>(h1, batch, fc1_w, fc1_b, fc2_w, fc2_b,
                                                fc3_w, fc3_b, sums);
    k_finish<<<(N_GRAPHS + 255) / 256, blk, 0, stream>>>(sums, batch, idx_a, idx_b,
                                                         out_pairs, out_util);
}